// Round 3
// baseline (505.307 us; speedup 1.0000x reference)
//
#include <hip/hip_runtime.h>

typedef float    f32x4 __attribute__((ext_vector_type(4)));
typedef _Float16 h16x8 __attribute__((ext_vector_type(8)));
typedef _Float16 h16x4 __attribute__((ext_vector_type(4)));

#define DEV __device__ __forceinline__
#define VMW(N) asm volatile("s_waitcnt vmcnt(" #N ")" ::: "memory")

// async global -> LDS, 16 bytes per lane; LDS dest = wave-uniform base + lane*16
DEV void async_load16(const void* g, void* l) {
  __builtin_amdgcn_global_load_lds((const __attribute__((address_space(1))) void*)g,
                                   (__attribute__((address_space(3))) void*)l,
                                   16, 0, 0);
}

// ---------------------------------------------------------------------------
// Shared geometry for the 256x256 8-phase GEMMs.
// LDS: [buf(2)][A | B(+32768)][kplane(2)][256 rows x 32 halves] = 128 KiB.
// Swizzle: 16B slot s of row r holds global k-chunk s ^ x(r), x(r)=(r^(r>>2))&3
// (r mod 16). Applied on BOTH sides: B via pre-swizzled global source with
// linear global_load_lds dest; A via linear global read + swizzled ds_write.
// ---------------------------------------------------------------------------

// ---------------------------------------------------------------------------
// fp32-A variant: C[16384,1024]fp16 = fp32 A @ fp16 Bw^T + bias.
// A is reg-staged (global fp32 -> regs -> cvt -> ds_write), B via gll.
// FIFO-vmcnt schedule (per wave, per steady iter):
//  ph1: VM(8)  awrite(b1,k0)            ph5: awrite(b0,k0) + B-gll(b0,k0)
//  ph2: VM(2)  awrite(b1,k1)            ph6: awrite(b0,k1) + B-gll(b0,k1)
//  ph3: aload(b0,k0)                    ph7: aload(b1,k0)  + B-gll(b1,k0)
//  ph4: aload(b0,k1) VM(8)              ph8: aload(b1,k1)  + B-gll(b1,k1) VM(12)
// Manual VMs gate cross-wave B visibility; compiler auto-vmcnt covers A regs.
// ---------------------------------------------------------------------------
__global__ __launch_bounds__(512, 2) void k_gemm_qkv_f32_256(
    const float* __restrict__ q, const float* __restrict__ k,
    const float* __restrict__ v, const _Float16* __restrict__ Wf,
    const float* __restrict__ bq, const float* __restrict__ bk,
    const float* __restrict__ bv, _Float16* __restrict__ proj) {
  constexpr size_t MW = 1024 * 1024, MA = (size_t)16384 * 1024;
  const int y = blockIdx.y;
  const float* __restrict__ A    = (y == 0) ? q  : (y == 1) ? k  : v;
  const float* __restrict__ bias = (y == 0) ? bq : (y == 1) ? bk : bv;
  const _Float16* __restrict__ Bw = Wf + y * MW;
  _Float16* __restrict__ C = proj + y * MA;

  __shared__ __align__(16) _Float16 lds[2 * 2 * 2 * 8192];  // 128 KiB
  char* ldsb = (char*)lds;

  const int tid  = threadIdx.x;
  const int lane = tid & 63;
  const int w    = tid >> 6;
  const int wm   = w >> 2, wn = w & 3;
  const int m16  = lane & 15, qq = lane >> 4;
  const int d    = blockIdx.x;
  const int bm   = (d & 7) + ((d >> 5) << 3);  // XCD swizzle, bijective on 256
  const int bn   = (d >> 3) & 3;
  const int rowbase = bm << 8;
  const int colbase = bn << 8;

  const int rr  = lane >> 2, ss = lane & 3;
  const int xsw = (rr ^ (rr >> 2)) & 3;
  const int sc  = (ss ^ xsw) * 8;  // pre-swizzled k-offset for B source (halves)

  // global addresses (element offsets)
  const size_t ar0 = (size_t)(rowbase + (w * 2 + 0) * 16 + rr) * 1024 + ss * 8;  // floats
  const size_t ar1 = (size_t)(rowbase + (w * 2 + 1) * 16 + rr) * 1024 + ss * 8;
  const size_t br0 = (size_t)(colbase + (w * 2 + 0) * 16 + rr) * 1024 + sc;      // halves
  const size_t br1 = (size_t)(colbase + (w * 2 + 1) * 16 + rr) * 1024 + sc;
  // swizzled ds_write byte offsets within a plane
  const int adst0 = (w * 2 + 0) * 1024 + rr * 64 + (ss ^ xsw) * 16;
  const int adst1 = (w * 2 + 1) * 1024 + rr * 64 + (ss ^ xsw) * 16;

  auto stBone = [&](int buf, int kk, int gk) {
    async_load16(Bw + br0 + gk + kk * 32,
                 ldsb + buf * 65536 + 32768 + kk * 16384 + (w * 2 + 0) * 1024);
    async_load16(Bw + br1 + gk + kk * 32,
                 ldsb + buf * 65536 + 32768 + kk * 16384 + (w * 2 + 1) * 1024);
  };

  f32x4 ra[4], rb[4];
  auto aload = [&](f32x4* r, int gkf) {
    r[0] = *(const f32x4*)(A + ar0 + gkf);
    r[1] = *(const f32x4*)(A + ar0 + gkf + 4);
    r[2] = *(const f32x4*)(A + ar1 + gkf);
    r[3] = *(const f32x4*)(A + ar1 + gkf + 4);
  };
  auto awrite = [&](const f32x4* r, int buf, int kk) {
    h16x8 o0, o1;
#pragma unroll
    for (int e = 0; e < 4; ++e) {
      o0[e]     = (_Float16)r[0][e];
      o0[4 + e] = (_Float16)r[1][e];
      o1[e]     = (_Float16)r[2][e];
      o1[4 + e] = (_Float16)r[3][e];
    }
    *(h16x8*)(ldsb + buf * 65536 + kk * 16384 + adst0) = o0;
    *(h16x8*)(ldsb + buf * 65536 + kk * 16384 + adst1) = o1;
  };

  // LDS read byte-offsets within a plane (swizzled)
  int aoff[8], boff[4];
#pragma unroll
  for (int mt = 0; mt < 8; ++mt) {
    const int r = wm * 128 + mt * 16 + m16;
    aoff[mt] = r * 64 + ((qq ^ ((r ^ (r >> 2)) & 3)) * 16);
  }
#pragma unroll
  for (int nt = 0; nt < 4; ++nt) {
    const int r = wn * 64 + nt * 16 + m16;
    boff[nt] = r * 64 + ((qq ^ ((r ^ (r >> 2)) & 3)) * 16);
  }

  f32x4 acc[8][4];
#pragma unroll
  for (int nt = 0; nt < 4; ++nt) {
    const float bv = bias[colbase + wn * 64 + nt * 16 + m16];
#pragma unroll
    for (int mt = 0; mt < 8; ++mt) acc[mt][nt] = {bv, bv, bv, bv};
  }

  // prologue: stage K-steps 0 (buf0) and 1 (buf1)
  aload(ra, 0); aload(rb, 32);
  awrite(ra, 0, 0);            // compiler auto-vmcnt gates the reg use
  awrite(rb, 0, 1);
  stBone(0, 0, 0); stBone(0, 1, 0);
  aload(ra, 64); stBone(1, 0, 64);
  aload(rb, 96); stBone(1, 1, 64);
  VMW(8);  // drains buf0 B-glls (oldest); leaves [B(b1k0)2, A(b1k1)4, B(b1k1)2]
  asm volatile("s_waitcnt lgkmcnt(0)" ::: "memory");
  __builtin_amdgcn_sched_barrier(0);
  __builtin_amdgcn_s_barrier();

  h16x8 bfr[4];

#define PH(BUF_, KK_, MH_, STAGE_)                                              \
  {                                                                             \
    const char* pA = ldsb + (BUF_) * 65536 + (KK_) * 16384;                     \
    const char* pB = pA + 32768;                                                \
    h16x8 a[4];                                                                 \
    _Pragma("unroll")                                                           \
    for (int m_ = 0; m_ < 4; ++m_)                                              \
      a[m_] = *(const h16x8*)(pA + aoff[(MH_) * 4 + m_]);                       \
    if ((MH_) == 0) {                                                           \
      _Pragma("unroll")                                                         \
      for (int n_ = 0; n_ < 4; ++n_)                                            \
        bfr[n_] = *(const h16x8*)(pB + boff[n_]);                               \
    }                                                                           \
    STAGE_                                                                      \
    asm volatile("s_waitcnt lgkmcnt(0)" ::: "memory");                          \
    __builtin_amdgcn_sched_barrier(0);                                          \
    __builtin_amdgcn_s_barrier();                                               \
    __builtin_amdgcn_s_setprio(1);                                              \
    _Pragma("unroll")                                                           \
    for (int m_ = 0; m_ < 4; ++m_)                                              \
      _Pragma("unroll")                                                         \
      for (int n_ = 0; n_ < 4; ++n_)                                            \
        acc[(MH_) * 4 + m_][n_] = __builtin_amdgcn_mfma_f32_16x16x32_f16(       \
            a[m_], bfr[n_], acc[(MH_) * 4 + m_][n_], 0, 0, 0);                  \
    __builtin_amdgcn_s_setprio(0);                                              \
    __builtin_amdgcn_s_barrier();                                               \
    __builtin_amdgcn_sched_barrier(0);                                          \
  }

  for (int i = 0; i < 7; ++i) {
    const int gA0 = (2 * i + 2) * 64, gA1 = (2 * i + 3) * 64;
    PH(0, 0, 0, { VMW(8); awrite(ra, 1, 0); })
    PH(0, 0, 1, { VMW(2); awrite(rb, 1, 1); })
    PH(0, 1, 0, { aload(ra, gA0); })
    PH(0, 1, 1, { aload(rb, gA0 + 32); VMW(8); })
    PH(1, 0, 0, { awrite(ra, 0, 0); stBone(0, 0, gA0); })
    PH(1, 0, 1, { awrite(rb, 0, 1); stBone(0, 1, gA0); })
    PH(1, 1, 0, { aload(ra, gA1); stBone(1, 0, gA1); })
    PH(1, 1, 1, { aload(rb, gA1 + 32); stBone(1, 1, gA1); VMW(12); })
  }
  // tail iter (K-steps 14,15): no further staging
  PH(0, 0, 0, { VMW(8); awrite(ra, 1, 0); })
  PH(0, 0, 1, { VMW(2); awrite(rb, 1, 1); })
  PH(0, 1, 0, {})
  PH(0, 1, 1, { VMW(0); })
  PH(1, 0, 0, {})
  PH(1, 0, 1, {})
  PH(1, 1, 0, {})
  PH(1, 1, 1, {})
#undef PH

#pragma unroll
  for (int mt = 0; mt < 8; ++mt) {
#pragma unroll
    for (int nt = 0; nt < 4; ++nt) {
      const int col = colbase + wn * 64 + nt * 16 + m16;
#pragma unroll
      for (int r = 0; r < 4; ++r) {
        const int row = rowbase + wm * 128 + mt * 16 + qq * 4 + r;
        C[(size_t)row * 1024 + col] = (_Float16)acc[mt][nt][r];
      }
    }
  }
}

// ---------------------------------------------------------------------------
// fp16-A 256x256 8-phase GEMM (round-1 verified) — used for the out-proj.
// ---------------------------------------------------------------------------
template <bool OF32>
DEV void gemm256_core(const _Float16* __restrict__ A, const _Float16* __restrict__ Bw,
                      const float* __restrict__ bias, void* Cv, int bm, int bn) {
  constexpr int N = 1024;
  __shared__ __align__(16) _Float16 lds[2 * 2 * 2 * 8192];  // 128 KiB
  char* ldsb = (char*)lds;

  const int tid  = threadIdx.x;
  const int lane = tid & 63;
  const int w    = tid >> 6;
  const int wm   = w >> 2, wn = w & 3;
  const int m16  = lane & 15, q = lane >> 4;
  const int rowbase = bm << 8;
  const int colbase = bn << 8;

  const int sr0 = (w * 2 + 0) * 16 + (lane >> 2);
  const int sr1 = (w * 2 + 1) * 16 + (lane >> 2);
  const int ss  = lane & 3;
  const int sc0 = ((ss ^ ((sr0 ^ (sr0 >> 2)) & 3)) * 8);
  const int sc1 = ((ss ^ ((sr1 ^ (sr1 >> 2)) & 3)) * 8);

  auto stA = [&](int buf, int kk, int gk) {
    async_load16(A + (size_t)(rowbase + sr0) * 1024 + gk + kk * 32 + sc0,
                 ldsb + buf * 65536 + kk * 16384 + (w * 2 + 0) * 1024);
    async_load16(A + (size_t)(rowbase + sr1) * 1024 + gk + kk * 32 + sc1,
                 ldsb + buf * 65536 + kk * 16384 + (w * 2 + 1) * 1024);
  };
  auto stB = [&](int buf, int kk, int gk) {
    async_load16(Bw + (size_t)(colbase + sr0) * 1024 + gk + kk * 32 + sc0,
                 ldsb + buf * 65536 + 32768 + kk * 16384 + (w * 2 + 0) * 1024);
    async_load16(Bw + (size_t)(colbase + sr1) * 1024 + gk + kk * 32 + sc1,
                 ldsb + buf * 65536 + 32768 + kk * 16384 + (w * 2 + 1) * 1024);
  };

  int aoff[8], boff[4];
#pragma unroll
  for (int mt = 0; mt < 8; ++mt) {
    const int r = wm * 128 + mt * 16 + m16;
    aoff[mt] = r * 64 + ((q ^ ((r ^ (r >> 2)) & 3)) * 16);
  }
#pragma unroll
  for (int nt = 0; nt < 4; ++nt) {
    const int r = wn * 64 + nt * 16 + m16;
    boff[nt] = r * 64 + ((q ^ ((r ^ (r >> 2)) & 3)) * 16);
  }

  f32x4 acc[8][4];
#pragma unroll
  for (int nt = 0; nt < 4; ++nt) {
    const float bv = bias[colbase + wn * 64 + nt * 16 + m16];
#pragma unroll
    for (int mt = 0; mt < 8; ++mt) acc[mt][nt] = {bv, bv, bv, bv};
  }

  stA(0, 0, 0); stB(0, 0, 0); stA(0, 1, 0); stB(0, 1, 0);
  stA(1, 0, 64); stB(1, 0, 64);
  asm volatile("s_waitcnt vmcnt(4)" ::: "memory");
  __builtin_amdgcn_s_barrier();
  __builtin_amdgcn_sched_barrier(0);

  h16x8 bfr[4];

#define PHASE(BUF_, KK_, MH_, STAGE_, VM_)                                      \
  {                                                                             \
    const char* pA = ldsb + (BUF_) * 65536 + (KK_) * 16384;                     \
    const char* pB = pA + 32768;                                                \
    h16x8 a[4];                                                                 \
    _Pragma("unroll")                                                           \
    for (int m_ = 0; m_ < 4; ++m_)                                              \
      a[m_] = *(const h16x8*)(pA + aoff[(MH_) * 4 + m_]);                       \
    if ((MH_) == 0) {                                                           \
      _Pragma("unroll")                                                         \
      for (int n_ = 0; n_ < 4; ++n_)                                            \
        bfr[n_] = *(const h16x8*)(pB + boff[n_]);                               \
    }                                                                           \
    STAGE_                                                                      \
    VM_                                                                         \
    __builtin_amdgcn_s_barrier();                                               \
    asm volatile("s_waitcnt lgkmcnt(0)" ::: "memory");                          \
    __builtin_amdgcn_sched_barrier(0);                                          \
    __builtin_amdgcn_s_setprio(1);                                              \
    _Pragma("unroll")                                                           \
    for (int m_ = 0; m_ < 4; ++m_)                                              \
      _Pragma("unroll")                                                         \
      for (int n_ = 0; n_ < 4; ++n_)                                            \
        acc[(MH_) * 4 + m_][n_] = __builtin_amdgcn_mfma_f32_16x16x32_f16(       \
            a[m_], bfr[n_], acc[(MH_) * 4 + m_][n_], 0, 0, 0);                  \
    __builtin_amdgcn_s_setprio(0);                                              \
    __builtin_amdgcn_s_barrier();                                               \
    __builtin_amdgcn_sched_barrier(0);                                          \
  }

  for (int i = 0; i < 7; ++i) {
    const int g1 = (2 * i + 1) * 64, g2 = (2 * i + 2) * 64, g3 = (2 * i + 3) * 64;
    PHASE(0, 0, 0, { stA(1, 1, g1); stB(1, 1, g1); }, {})
    PHASE(0, 0, 1, {}, {})
    PHASE(0, 1, 0, { stA(0, 0, g2); }, {})
    PHASE(0, 1, 1, { stB(0, 0, g2); },
          { asm volatile("s_waitcnt vmcnt(4)" ::: "memory"); })
    PHASE(1, 0, 0, { stA(0, 1, g2); stB(0, 1, g2); }, {})
    PHASE(1, 0, 1, {}, {})
    PHASE(1, 1, 0, { stA(1, 0, g3); }, {})
    PHASE(1, 1, 1, { stB(1, 0, g3); },
          { asm volatile("s_waitcnt vmcnt(4)" ::: "memory"); })
  }
  {
    const int g1 = 15 * 64;
    PHASE(0, 0, 0, { stA(1, 1, g1); stB(1, 1, g1); }, {})
    PHASE(0, 0, 1, {}, {})
    PHASE(0, 1, 0, {}, {})
    PHASE(0, 1, 1, {}, { asm volatile("s_waitcnt vmcnt(0)" ::: "memory"); })
    PHASE(1, 0, 0, {}, {})
    PHASE(1, 0, 1, {}, {})
    PHASE(1, 1, 0, {}, {})
    PHASE(1, 1, 1, {}, {})
  }
#undef PHASE

#pragma unroll
  for (int mt = 0; mt < 8; ++mt) {
#pragma unroll
    for (int nt = 0; nt < 4; ++nt) {
      const int col = colbase + wn * 64 + nt * 16 + m16;
#pragma unroll
      for (int r = 0; r < 4; ++r) {
        const int row = rowbase + wm * 128 + mt * 16 + q * 4 + r;
        if constexpr (OF32)
          ((float*)Cv)[(size_t)row * N + col] = acc[mt][nt][r];
        else
          ((_Float16*)Cv)[(size_t)row * N + col] = (_Float16)acc[mt][nt][r];
      }
    }
  }
}

// ---------------------------------------------------------------------------
// Legacy 128x128 GEMM core (small-workspace fallback only).
// ---------------------------------------------------------------------------
template <int AMODE, bool OF32>
DEV void gemm_core(const void* Av, const _Float16* __restrict__ Bw,
                   const float* __restrict__ bias, void* Cv) {
  constexpr int K = 1024, N = 1024;
  __shared__ __align__(16) _Float16 As[128 * 32];
  __shared__ __align__(16) _Float16 Bs[128 * 32];

  const int tid  = threadIdx.x;
  const int lane = tid & 63;
  const int w    = tid >> 6;
  const int d    = blockIdx.x;
  const int bm   = (d & 7) | ((d >> 6) << 3);
  const int bn   = (d >> 3) & 7;
  const int rowbase = bm << 7;
  const int colbase = bn << 7;
  const int wm = w >> 1, wn = w & 1;
  const int m16 = lane & 15, q = lane >> 4;
  const int brow = lane >> 2;
  const int bcol = (lane & 3) * 8;

  f32x4 acc[4][4];
#pragma unroll
  for (int nt = 0; nt < 4; ++nt) {
    const float bv = bias[colbase + wn * 64 + nt * 16 + m16];
#pragma unroll
    for (int mt = 0; mt < 4; ++mt) acc[mt][nt] = {bv, bv, bv, bv};
  }

  for (int ki = 0; ki < 32; ++ki) {
    const int k0 = ki * 32;
    if constexpr (AMODE == 0) {
      const _Float16* A = (const _Float16*)Av;
#pragma unroll
      for (int t = 0; t < 2; ++t)
        async_load16(A + (size_t)(rowbase + (w * 2 + t) * 16 + brow) * K + k0 + bcol,
                     &As[(w * 2 + t) * 512]);
    } else {
      const float* A = (const float*)Av;
#pragma unroll
      for (int i = 0; i < 4; ++i) {
        const int f = tid + i * 256;
        const int r = f >> 3, c4 = f & 7;
        const float4 v = *(const float4*)(A + (size_t)(rowbase + r) * K + k0 + c4 * 4);
        h16x4 o = {(_Float16)v.x, (_Float16)v.y, (_Float16)v.z, (_Float16)v.w};
        *(h16x4*)&As[r * 32 + c4 * 4] = o;
      }
    }
#pragma unroll
    for (int t = 0; t < 2; ++t)
      async_load16(Bw + (size_t)(colbase + (w * 2 + t) * 16 + brow) * K + k0 + bcol,
                   &Bs[(w * 2 + t) * 512]);
    __syncthreads();

    h16x8 af[4], bfr[4];
#pragma unroll
    for (int mt = 0; mt < 4; ++mt)
      af[mt] = *(const h16x8*)&As[(wm * 64 + mt * 16 + m16) * 32 + q * 8];
#pragma unroll
    for (int nt = 0; nt < 4; ++nt)
      bfr[nt] = *(const h16x8*)&Bs[(wn * 64 + nt * 16 + m16) * 32 + q * 8];
#pragma unroll
    for (int mt = 0; mt < 4; ++mt)
#pragma unroll
      for (int nt = 0; nt < 4; ++nt)
        acc[mt][nt] = __builtin_amdgcn_mfma_f32_16x16x32_f16(af[mt], bfr[nt], acc[mt][nt], 0, 0, 0);
    __syncthreads();
  }

#pragma unroll
  for (int mt = 0; mt < 4; ++mt) {
#pragma unroll
    for (int nt = 0; nt < 4; ++nt) {
      const int col = colbase + wn * 64 + nt * 16 + m16;
#pragma unroll
      for (int r = 0; r < 4; ++r) {
        const int row = rowbase + wm * 64 + mt * 16 + q * 4 + r;
        if constexpr (OF32)
          ((float*)Cv)[(size_t)row * N + col] = acc[mt][nt][r];
        else
          ((_Float16*)Cv)[(size_t)row * N + col] = (_Float16)acc[mt][nt][r];
      }
    }
  }
}

// weights fp32 -> fp16 (4 matrices of 1024x1024, contiguous dst)
__global__ __launch_bounds__(256) void k_cvt_w(const float* __restrict__ Wq,
                                               const float* __restrict__ Wk,
                                               const float* __restrict__ Wv,
                                               const float* __restrict__ Wo,
                                               _Float16* __restrict__ dst) {
  const float* src;
  switch (blockIdx.y) {
    case 0: src = Wq; break;
    case 1: src = Wk; break;
    case 2: src = Wv; break;
    default: src = Wo; break;
  }
  _Float16* d = dst + (size_t)blockIdx.y * (1024 * 1024);
  const int idx = blockIdx.x * 256 + threadIdx.x;
  const float4 v = ((const float4*)src)[idx];
  h16x4 o = {(_Float16)v.x, (_Float16)v.y, (_Float16)v.z, (_Float16)v.w};
  ((h16x4*)d)[idx] = o;
}

__global__ __launch_bounds__(512, 2) void k_gemm_out_256(const _Float16* __restrict__ ao,
                                                         const _Float16* __restrict__ Wof,
                                                         const float* __restrict__ bo,
                                                         float* __restrict__ C) {
  const int d  = blockIdx.x;
  const int bm = (d & 7) + ((d >> 5) << 3);
  const int bn = (d >> 3) & 3;
  gemm256_core<true>(ao, Wof, bo, C, bm, bn);
}

__global__ __launch_bounds__(256) void k_gemm_qkv_f32_legacy(
    const float* __restrict__ q, const float* __restrict__ k,
    const float* __restrict__ v, const _Float16* __restrict__ Wf,
    const float* __restrict__ bq, const float* __restrict__ bk,
    const float* __restrict__ bv, _Float16* __restrict__ proj) {
  constexpr size_t MW = 1024 * 1024, MA = (size_t)16384 * 1024;
  const int y = blockIdx.y;
  const float* A    = (y == 0) ? q  : (y == 1) ? k  : v;
  const float* bias = (y == 0) ? bq : (y == 1) ? bk : bv;
  gemm_core<1, false>(A, Wf + y * MW, bias, proj + y * MA);
}

// ---------------------------------------------------------------------------
// Per-position local attention via MFMA. One WAVE per position.
// ---------------------------------------------------------------------------
__global__ __launch_bounds__(256) void k_attn(const _Float16* __restrict__ qp,
                                              const _Float16* __restrict__ kp,
                                              const _Float16* __restrict__ vp,
                                              _Float16* __restrict__ op) {
  constexpr int RS2 = 20;
  __shared__ __align__(16) _Float16 vsh[4][64 * RS2];
  const int w    = threadIdx.x >> 6;
  const int lane = threadIdx.x & 63;
  const int g    = lane >> 4;
  const int t    = lane & 15;
  const size_t base = ((size_t)blockIdx.x * 4 + w) * 1024;

  {
    h16x8 v0 = *(const h16x8*)(vp + base + lane * 16);
    h16x8 v1 = *(const h16x8*)(vp + base + lane * 16 + 8);
    _Float16* vr = &vsh[w][lane * RS2];
    h16x4 a0, a1, a2, a3;
#pragma unroll
    for (int e = 0; e < 4; ++e) {
      a0[e] = v0[e]; a1[e] = v0[4 + e]; a2[e] = v1[e]; a3[e] = v1[4 + e];
    }
    *(h16x4*)(vr + 0)  = a0;
    *(h16x4*)(vr + 4)  = a1;
    *(h16x4*)(vr + 8)  = a2;
    *(h16x4*)(vr + 12) = a3;
  }

  h16x4 kA[4], qB[4];
#pragma unroll
  for (int jt = 0; jt < 4; ++jt) {
    kA[jt] = *(const h16x4*)(kp + base + (jt * 16 + t) * 16 + g * 4);
    qB[jt] = *(const h16x4*)(qp + base + (jt * 16 + t) * 16 + g * 4);
  }

  f32x4 st[4][4];
#pragma unroll
  for (int jt = 0; jt < 4; ++jt)
#pragma unroll
    for (int nt = 0; nt < 4; ++nt)
      st[jt][nt] = __builtin_amdgcn_mfma_f32_16x16x16f16(
          kA[jt], qB[nt], (f32x4){0.f, 0.f, 0.f, 0.f}, 0, 0, 0);

  h16x4 pb[4][4];
  float inv[4];
#pragma unroll
  for (int nt = 0; nt < 4; ++nt) {
    float mx = -3.0e38f;
#pragma unroll
    for (int jt = 0; jt < 4; ++jt)
#pragma unroll
      for (int r = 0; r < 4; ++r) mx = fmaxf(mx, st[jt][nt][r]);
    mx = fmaxf(mx, __shfl_xor(mx, 16));
    mx = fmaxf(mx, __shfl_xor(mx, 32));
    float sum = 0.f;
#pragma unroll
    for (int jt = 0; jt < 4; ++jt) {
#pragma unroll
      for (int r = 0; r < 4; ++r) {
        const float p = __expf((st[jt][nt][r] - mx) * 32.0f);
        sum += p;
        pb[jt][nt][r] = (_Float16)p;
      }
    }
    sum += __shfl_xor(sum, 16);
    sum += __shfl_xor(sum, 32);
    inv[nt] = 1.0f / sum;
  }

  h16x4 vA[4];
#pragma unroll
  for (int kt = 0; kt < 4; ++kt)
#pragma unroll
    for (int e = 0; e < 4; ++e)
      vA[kt][e] = vsh[w][(kt * 16 + g * 4 + e) * RS2 + t];

#pragma unroll
  for (int it = 0; it < 4; ++it) {
    f32x4 ot = {0.f, 0.f, 0.f, 0.f};
#pragma unroll
    for (int kt = 0; kt < 4; ++kt)
      ot = __builtin_amdgcn_mfma_f32_16x16x16f16(vA[kt], pb[kt][it], ot, 0, 0, 0);
    h16x4 o;
#pragma unroll
    for (int r = 0; r < 4; ++r) o[r] = (_Float16)(ot[r] * inv[it]);
    *(h16x4*)(op + base + (it * 16 + t) * 16 + g * 4) = o;
  }
}

extern "C" void kernel_launch(void* const* d_in, const int* in_sizes, int n_in,
                              void* d_out, int out_size, void* d_ws, size_t ws_size,
                              hipStream_t stream) {
  const float* query = (const float*)d_in[0];
  const float* key_  = (const float*)d_in[1];
  const float* value = (const float*)d_in[2];
  const float* Wq    = (const float*)d_in[3];
  const float* bq    = (const float*)d_in[4];
  const float* Wk    = (const float*)d_in[5];
  const float* bk    = (const float*)d_in[6];
  const float* Wv    = (const float*)d_in[7];
  const float* bv    = (const float*)d_in[8];
  const float* Wo    = (const float*)d_in[9];
  const float* bo    = (const float*)d_in[10];

  constexpr size_t MW = 1024 * 1024;
  constexpr size_t MA = (size_t)16384 * 1024;

  _Float16* Wf   = (_Float16*)d_ws;   // 8 MB fp16 weights
  _Float16* proj = Wf + 4 * MW;       // 96 MB
  _Float16* ao   = proj + 3 * MA;     // 32 MB
  const size_t need = (4 * MW + 4 * MA) * sizeof(_Float16);  // 136 MB

  k_cvt_w<<<dim3(1024, 4), 256, 0, stream>>>(Wq, Wk, Wv, Wo, Wf);

  if (ws_size >= need) {
    k_gemm_qkv_f32_256<<<dim3(256, 3), 512, 0, stream>>>(query, key_, value, Wf,
                                                         bq, bk, bv, proj);
    k_attn<<<4096, 256, 0, stream>>>(proj, proj + MA, proj + 2 * MA, ao);
    k_gemm_out_256<<<256, 512, 0, stream>>>(ao, Wf + 3 * MW, bo, (float*)d_out);
  } else {
    k_gemm_qkv_f32_legacy<<<dim3(1024, 3), 256, 0, stream>>>(query, key_, value, Wf,
                                                             bq, bk, bv, proj);
    k_attn<<<4096, 256, 0, stream>>>(proj, proj + MA, proj + 2 * MA, ao);
    k_gemm_out_256<<<256, 512, 0, stream>>>(ao, Wf + 3 * MW, bo, (float*)d_out);
  }
}

// Round 4
// 414.284 us; speedup vs baseline: 1.2197x; 1.2197x over previous
//
#include <hip/hip_runtime.h>

typedef float    f32x4 __attribute__((ext_vector_type(4)));
typedef _Float16 h16x8 __attribute__((ext_vector_type(8)));
typedef _Float16 h16x4 __attribute__((ext_vector_type(4)));

#define DEV __device__ __forceinline__

// async global -> LDS, 16 bytes per lane; LDS dest = wave-uniform base + lane*16
DEV void async_load16(const void* g, void* l) {
  __builtin_amdgcn_global_load_lds((const __attribute__((address_space(1))) void*)g,
                                   (__attribute__((address_space(3))) void*)l,
                                   16, 0, 0);
}

// ---------------------------------------------------------------------------
// fp16-A 256x256 8-phase GEMM (round-1 verified; round-2 measured 126.6 us,
// 815 TF ~= the 8-phase structure ceiling at K=1024).
// LDS: [buf(2)][A | B(+32768)][kplane(2)][256 rows x 32 halves] = 128 KiB.
// Swizzle: 16B slot s of row r holds global k-chunk s ^ ((r^(r>>2))&3),
// applied on BOTH sides via pre-swizzled global source + swizzled ds_read.
// Counted vmcnt(4) at phases 4/8 only (never 0 in steady state).
// ---------------------------------------------------------------------------
template <bool OF32>
DEV void gemm256_core(const _Float16* __restrict__ A, const _Float16* __restrict__ Bw,
                      const float* __restrict__ bias, void* Cv, int bm, int bn) {
  constexpr int N = 1024;
  __shared__ __align__(16) _Float16 lds[2 * 2 * 2 * 8192];  // 128 KiB
  char* ldsb = (char*)lds;

  const int tid  = threadIdx.x;
  const int lane = tid & 63;
  const int w    = tid >> 6;
  const int wm   = w >> 2, wn = w & 3;
  const int m16  = lane & 15, q = lane >> 4;
  const int rowbase = bm << 8;
  const int colbase = bn << 8;

  const int sr0 = (w * 2 + 0) * 16 + (lane >> 2);
  const int sr1 = (w * 2 + 1) * 16 + (lane >> 2);
  const int ss  = lane & 3;
  const int sc0 = ((ss ^ ((sr0 ^ (sr0 >> 2)) & 3)) * 8);
  const int sc1 = ((ss ^ ((sr1 ^ (sr1 >> 2)) & 3)) * 8);

  auto stA = [&](int buf, int kk, int gk) {
    async_load16(A + (size_t)(rowbase + sr0) * 1024 + gk + kk * 32 + sc0,
                 ldsb + buf * 65536 + kk * 16384 + (w * 2 + 0) * 1024);
    async_load16(A + (size_t)(rowbase + sr1) * 1024 + gk + kk * 32 + sc1,
                 ldsb + buf * 65536 + kk * 16384 + (w * 2 + 1) * 1024);
  };
  auto stB = [&](int buf, int kk, int gk) {
    async_load16(Bw + (size_t)(colbase + sr0) * 1024 + gk + kk * 32 + sc0,
                 ldsb + buf * 65536 + 32768 + kk * 16384 + (w * 2 + 0) * 1024);
    async_load16(Bw + (size_t)(colbase + sr1) * 1024 + gk + kk * 32 + sc1,
                 ldsb + buf * 65536 + 32768 + kk * 16384 + (w * 2 + 1) * 1024);
  };

  int aoff[8], boff[4];
#pragma unroll
  for (int mt = 0; mt < 8; ++mt) {
    const int r = wm * 128 + mt * 16 + m16;
    aoff[mt] = r * 64 + ((q ^ ((r ^ (r >> 2)) & 3)) * 16);
  }
#pragma unroll
  for (int nt = 0; nt < 4; ++nt) {
    const int r = wn * 64 + nt * 16 + m16;
    boff[nt] = r * 64 + ((q ^ ((r ^ (r >> 2)) & 3)) * 16);
  }

  f32x4 acc[8][4];
#pragma unroll
  for (int nt = 0; nt < 4; ++nt) {
    const float bv = bias[colbase + wn * 64 + nt * 16 + m16];
#pragma unroll
    for (int mt = 0; mt < 8; ++mt) acc[mt][nt] = {bv, bv, bv, bv};
  }

  stA(0, 0, 0); stB(0, 0, 0); stA(0, 1, 0); stB(0, 1, 0);
  stA(1, 0, 64); stB(1, 0, 64);
  asm volatile("s_waitcnt vmcnt(4)" ::: "memory");
  __builtin_amdgcn_s_barrier();
  __builtin_amdgcn_sched_barrier(0);

  h16x8 bfr[4];

#define PHASE(BUF_, KK_, MH_, STAGE_, VM_)                                      \
  {                                                                             \
    const char* pA = ldsb + (BUF_) * 65536 + (KK_) * 16384;                     \
    const char* pB = pA + 32768;                                                \
    h16x8 a[4];                                                                 \
    _Pragma("unroll")                                                           \
    for (int m_ = 0; m_ < 4; ++m_)                                              \
      a[m_] = *(const h16x8*)(pA + aoff[(MH_) * 4 + m_]);                       \
    if ((MH_) == 0) {                                                           \
      _Pragma("unroll")                                                         \
      for (int n_ = 0; n_ < 4; ++n_)                                            \
        bfr[n_] = *(const h16x8*)(pB + boff[n_]);                               \
    }                                                                           \
    STAGE_                                                                      \
    VM_                                                                         \
    __builtin_amdgcn_s_barrier();                                               \
    asm volatile("s_waitcnt lgkmcnt(0)" ::: "memory");                          \
    __builtin_amdgcn_sched_barrier(0);                                          \
    __builtin_amdgcn_s_setprio(1);                                              \
    _Pragma("unroll")                                                           \
    for (int m_ = 0; m_ < 4; ++m_)                                              \
      _Pragma("unroll")                                                         \
      for (int n_ = 0; n_ < 4; ++n_)                                            \
        acc[(MH_) * 4 + m_][n_] = __builtin_amdgcn_mfma_f32_16x16x32_f16(       \
            a[m_], bfr[n_], acc[(MH_) * 4 + m_][n_], 0, 0, 0);                  \
    __builtin_amdgcn_s_setprio(0);                                              \
    __builtin_amdgcn_s_barrier();                                               \
    __builtin_amdgcn_sched_barrier(0);                                          \
  }

  for (int i = 0; i < 7; ++i) {
    const int g1 = (2 * i + 1) * 64, g2 = (2 * i + 2) * 64, g3 = (2 * i + 3) * 64;
    PHASE(0, 0, 0, { stA(1, 1, g1); stB(1, 1, g1); }, {})
    PHASE(0, 0, 1, {}, {})
    PHASE(0, 1, 0, { stA(0, 0, g2); }, {})
    PHASE(0, 1, 1, { stB(0, 0, g2); },
          { asm volatile("s_waitcnt vmcnt(4)" ::: "memory"); })
    PHASE(1, 0, 0, { stA(0, 1, g2); stB(0, 1, g2); }, {})
    PHASE(1, 0, 1, {}, {})
    PHASE(1, 1, 0, { stA(1, 0, g3); }, {})
    PHASE(1, 1, 1, { stB(1, 0, g3); },
          { asm volatile("s_waitcnt vmcnt(4)" ::: "memory"); })
  }
  {
    const int g1 = 15 * 64;
    PHASE(0, 0, 0, { stA(1, 1, g1); stB(1, 1, g1); }, {})
    PHASE(0, 0, 1, {}, {})
    PHASE(0, 1, 0, {}, {})
    PHASE(0, 1, 1, {}, { asm volatile("s_waitcnt vmcnt(0)" ::: "memory"); })
    PHASE(1, 0, 0, {}, {})
    PHASE(1, 0, 1, {}, {})
    PHASE(1, 1, 0, {}, {})
    PHASE(1, 1, 1, {}, {})
  }
#undef PHASE

#pragma unroll
  for (int mt = 0; mt < 8; ++mt) {
#pragma unroll
    for (int nt = 0; nt < 4; ++nt) {
      const int col = colbase + wn * 64 + nt * 16 + m16;
#pragma unroll
      for (int r = 0; r < 4; ++r) {
        const int row = rowbase + wm * 128 + mt * 16 + q * 4 + r;
        if constexpr (OF32)
          ((float*)Cv)[(size_t)row * N + col] = acc[mt][nt][r];
        else
          ((_Float16*)Cv)[(size_t)row * N + col] = (_Float16)acc[mt][nt][r];
      }
    }
  }
}

// ---------------------------------------------------------------------------
// Legacy 128x128 GEMM core (small-workspace fallback only).
// ---------------------------------------------------------------------------
template <int AMODE, bool OF32>
DEV void gemm_core(const void* Av, const _Float16* __restrict__ Bw,
                   const float* __restrict__ bias, void* Cv) {
  constexpr int K = 1024, N = 1024;
  __shared__ __align__(16) _Float16 As[128 * 32];
  __shared__ __align__(16) _Float16 Bs[128 * 32];

  const int tid  = threadIdx.x;
  const int lane = tid & 63;
  const int w    = tid >> 6;
  const int d    = blockIdx.x;
  const int bm   = (d & 7) | ((d >> 6) << 3);
  const int bn   = (d >> 3) & 7;
  const int rowbase = bm << 7;
  const int colbase = bn << 7;
  const int wm = w >> 1, wn = w & 1;
  const int m16 = lane & 15, q = lane >> 4;
  const int brow = lane >> 2;
  const int bcol = (lane & 3) * 8;

  f32x4 acc[4][4];
#pragma unroll
  for (int nt = 0; nt < 4; ++nt) {
    const float bv = bias[colbase + wn * 64 + nt * 16 + m16];
#pragma unroll
    for (int mt = 0; mt < 4; ++mt) acc[mt][nt] = {bv, bv, bv, bv};
  }

  for (int ki = 0; ki < 32; ++ki) {
    const int k0 = ki * 32;
    if constexpr (AMODE == 0) {
      const _Float16* A = (const _Float16*)Av;
#pragma unroll
      for (int t = 0; t < 2; ++t)
        async_load16(A + (size_t)(rowbase + (w * 2 + t) * 16 + brow) * K + k0 + bcol,
                     &As[(w * 2 + t) * 512]);
    } else {
      const float* A = (const float*)Av;
#pragma unroll
      for (int i = 0; i < 4; ++i) {
        const int f = tid + i * 256;
        const int r = f >> 3, c4 = f & 7;
        const float4 v = *(const float4*)(A + (size_t)(rowbase + r) * K + k0 + c4 * 4);
        h16x4 o = {(_Float16)v.x, (_Float16)v.y, (_Float16)v.z, (_Float16)v.w};
        *(h16x4*)&As[r * 32 + c4 * 4] = o;
      }
    }
#pragma unroll
    for (int t = 0; t < 2; ++t)
      async_load16(Bw + (size_t)(colbase + (w * 2 + t) * 16 + brow) * K + k0 + bcol,
                   &Bs[(w * 2 + t) * 512]);
    __syncthreads();

    h16x8 af[4], bfr[4];
#pragma unroll
    for (int mt = 0; mt < 4; ++mt)
      af[mt] = *(const h16x8*)&As[(wm * 64 + mt * 16 + m16) * 32 + q * 8];
#pragma unroll
    for (int nt = 0; nt < 4; ++nt)
      bfr[nt] = *(const h16x8*)&Bs[(wn * 64 + nt * 16 + m16) * 32 + q * 8];
#pragma unroll
    for (int mt = 0; mt < 4; ++mt)
#pragma unroll
      for (int nt = 0; nt < 4; ++nt)
        acc[mt][nt] = __builtin_amdgcn_mfma_f32_16x16x32_f16(af[mt], bfr[nt], acc[mt][nt], 0, 0, 0);
    __syncthreads();
  }

#pragma unroll
  for (int mt = 0; mt < 4; ++mt) {
#pragma unroll
    for (int nt = 0; nt < 4; ++nt) {
      const int col = colbase + wn * 64 + nt * 16 + m16;
#pragma unroll
      for (int r = 0; r < 4; ++r) {
        const int row = rowbase + wm * 64 + mt * 16 + q * 4 + r;
        if constexpr (OF32)
          ((float*)Cv)[(size_t)row * N + col] = acc[mt][nt][r];
        else
          ((_Float16*)Cv)[(size_t)row * N + col] = (_Float16)acc[mt][nt][r];
      }
    }
  }
}

// ---------------------------------------------------------------------------
// ONE conversion kernel: weights (4x 1M fp32) + activations (3x 16M fp32)
// -> fp16 into [Wf | xf] (contiguous). Saves a launch (~20 us fixed cost).
// Regions are block-aligned: weights = first 2^20 float4s (4096 blocks),
// activations = next 3*2^22 float4s.
// ---------------------------------------------------------------------------
__global__ __launch_bounds__(256) void k_cvt_all(const float* __restrict__ Wq,
                                                 const float* __restrict__ Wk,
                                                 const float* __restrict__ Wv,
                                                 const float* __restrict__ Wo,
                                                 const float* __restrict__ q,
                                                 const float* __restrict__ k,
                                                 const float* __restrict__ v,
                                                 _Float16* __restrict__ dst) {
  const size_t i4 = (size_t)blockIdx.x * 256 + threadIdx.x;
  const float* src;
  size_t off;
  if (i4 < (1u << 20)) {
    const int wi = (int)(i4 >> 18);
    src = (wi == 0) ? Wq : (wi == 1) ? Wk : (wi == 2) ? Wv : Wo;
    off = i4 & ((1u << 18) - 1);
  } else {
    const size_t j = i4 - (1u << 20);
    const int ai = (int)(j >> 22);
    src = (ai == 0) ? q : (ai == 1) ? k : v;
    off = j & ((1u << 22) - 1);
  }
  const float4 vv = ((const float4*)src)[off];
  h16x4 o = {(_Float16)vv.x, (_Float16)vv.y, (_Float16)vv.z, (_Float16)vv.w};
  ((h16x4*)dst)[i4] = o;
}

// weights-only conversion (fallback path)
__global__ __launch_bounds__(256) void k_cvt_w(const float* __restrict__ Wq,
                                               const float* __restrict__ Wk,
                                               const float* __restrict__ Wv,
                                               const float* __restrict__ Wo,
                                               _Float16* __restrict__ dst) {
  const float* src;
  switch (blockIdx.y) {
    case 0: src = Wq; break;
    case 1: src = Wk; break;
    case 2: src = Wv; break;
    default: src = Wo; break;
  }
  _Float16* d = dst + (size_t)blockIdx.y * (1024 * 1024);
  const int idx = blockIdx.x * 256 + threadIdx.x;
  const float4 v = ((const float4*)src)[idx];
  h16x4 o = {(_Float16)v.x, (_Float16)v.y, (_Float16)v.z, (_Float16)v.w};
  ((h16x4*)d)[idx] = o;
}

__global__ __launch_bounds__(512, 2) void k_gemm_qkv_256(const _Float16* __restrict__ xf,
                                                         const _Float16* __restrict__ Wf,
                                                         const float* __restrict__ bq,
                                                         const float* __restrict__ bk,
                                                         const float* __restrict__ bv,
                                                         _Float16* __restrict__ proj) {
  constexpr size_t MW = 1024 * 1024, MA = (size_t)16384 * 1024;
  const int y = blockIdx.y;
  const float* bias = (y == 0) ? bq : (y == 1) ? bk : bv;
  const int d  = blockIdx.x;
  const int bm = (d & 7) + ((d >> 5) << 3);  // XCD swizzle, bijective on 256
  const int bn = (d >> 3) & 3;
  gemm256_core<false>(xf + y * MA, Wf + y * MW, bias, proj + y * MA, bm, bn);
}

__global__ __launch_bounds__(512, 2) void k_gemm_out_256(const _Float16* __restrict__ ao,
                                                         const _Float16* __restrict__ Wof,
                                                         const float* __restrict__ bo,
                                                         float* __restrict__ C) {
  const int d  = blockIdx.x;
  const int bm = (d & 7) + ((d >> 5) << 3);
  const int bn = (d >> 3) & 3;
  gemm256_core<true>(ao, Wof, bo, C, bm, bn);
}

__global__ __launch_bounds__(256) void k_gemm_qkv_f32_legacy(
    const float* __restrict__ q, const float* __restrict__ k,
    const float* __restrict__ v, const _Float16* __restrict__ Wf,
    const float* __restrict__ bq, const float* __restrict__ bk,
    const float* __restrict__ bv, _Float16* __restrict__ proj) {
  constexpr size_t MW = 1024 * 1024, MA = (size_t)16384 * 1024;
  const int y = blockIdx.y;
  const float* A    = (y == 0) ? q  : (y == 1) ? k  : v;
  const float* bias = (y == 0) ? bq : (y == 1) ? bk : bv;
  gemm_core<1, false>(A, Wf + y * MW, bias, proj + y * MA);
}

// ---------------------------------------------------------------------------
// Per-position local attention via MFMA. One WAVE per position.
// MFMA math identical to round-1 (verified); data movement reworked:
//  - q,k,v staged via fully-coalesced 2x16B-per-lane loads into padded LDS
//    (RS=20 halves: b64 frag reads hit every bank exactly 4x -> optimal),
//  - fragments gathered from LDS (was: fragmented 8B global loads),
//  - output assembled in LDS (qsh reused) -> 2x16B coalesced global stores
//    (was: 4x 8B scattered stores).
// No __syncthreads: each wave owns its LDS slices.
// ---------------------------------------------------------------------------
__global__ __launch_bounds__(256) void k_attn(const _Float16* __restrict__ qp,
                                              const _Float16* __restrict__ kp,
                                              const _Float16* __restrict__ vp,
                                              _Float16* __restrict__ op) {
  constexpr int RS = 20;  // halves per row (16 data + 4 pad)
  __shared__ __align__(16) _Float16 qsh[4][64 * RS];
  __shared__ __align__(16) _Float16 ksh[4][64 * RS];
  __shared__ __align__(16) _Float16 vsh[4][64 * RS];
  const int w    = threadIdx.x >> 6;
  const int lane = threadIdx.x & 63;
  const int g    = lane >> 4;   // k-chunk group
  const int t    = lane & 15;   // row/col-within-tile
  const size_t base = ((size_t)blockIdx.x * 4 + w) * 1024;

  // coalesced stage: lane owns row `lane` (16 halves) of each tensor
  {
    h16x8 q0 = *(const h16x8*)(qp + base + lane * 16);
    h16x8 q1 = *(const h16x8*)(qp + base + lane * 16 + 8);
    h16x8 k0 = *(const h16x8*)(kp + base + lane * 16);
    h16x8 k1 = *(const h16x8*)(kp + base + lane * 16 + 8);
    h16x8 v0 = *(const h16x8*)(vp + base + lane * 16);
    h16x8 v1 = *(const h16x8*)(vp + base + lane * 16 + 8);
    _Float16* qr = &qsh[w][lane * RS];
    _Float16* kr = &ksh[w][lane * RS];
    _Float16* vr = &vsh[w][lane * RS];
#pragma unroll
    for (int c = 0; c < 2; ++c) {
      h16x4 a;
#pragma unroll
      for (int e = 0; e < 4; ++e) a[e] = q0[c * 4 + e];
      *(h16x4*)(qr + c * 4) = a;
#pragma unroll
      for (int e = 0; e < 4; ++e) a[e] = q1[c * 4 + e];
      *(h16x4*)(qr + 8 + c * 4) = a;
#pragma unroll
      for (int e = 0; e < 4; ++e) a[e] = k0[c * 4 + e];
      *(h16x4*)(kr + c * 4) = a;
#pragma unroll
      for (int e = 0; e < 4; ++e) a[e] = k1[c * 4 + e];
      *(h16x4*)(kr + 8 + c * 4) = a;
#pragma unroll
      for (int e = 0; e < 4; ++e) a[e] = v0[c * 4 + e];
      *(h16x4*)(vr + c * 4) = a;
#pragma unroll
      for (int e = 0; e < 4; ++e) a[e] = v1[c * 4 + e];
      *(h16x4*)(vr + 8 + c * 4) = a;
    }
  }

  // A-frags from k (row jt*16+t, k-chunk g*4), B-frags from q (same pattern)
  h16x4 kA[4], qB[4];
#pragma unroll
  for (int jt = 0; jt < 4; ++jt) {
    kA[jt] = *(const h16x4*)&ksh[w][(jt * 16 + t) * RS + g * 4];
    qB[jt] = *(const h16x4*)&qsh[w][(jt * 16 + t) * RS + g * 4];
  }

  // S^T = k @ q^T  (16 tiles)
  f32x4 st[4][4];
#pragma unroll
  for (int jt = 0; jt < 4; ++jt)
#pragma unroll
    for (int nt = 0; nt < 4; ++nt)
      st[jt][nt] = __builtin_amdgcn_mfma_f32_16x16x16f16(
          kA[jt], qB[nt], (f32x4){0.f, 0.f, 0.f, 0.f}, 0, 0, 0);

  // softmax over j (per column i = nt*16+t); P^T accs are PV B-frags directly
  h16x4 pb[4][4];
  float inv[4];
#pragma unroll
  for (int nt = 0; nt < 4; ++nt) {
    float mx = -3.0e38f;
#pragma unroll
    for (int jt = 0; jt < 4; ++jt)
#pragma unroll
      for (int r = 0; r < 4; ++r) mx = fmaxf(mx, st[jt][nt][r]);
    mx = fmaxf(mx, __shfl_xor(mx, 16));
    mx = fmaxf(mx, __shfl_xor(mx, 32));
    float sum = 0.f;
#pragma unroll
    for (int jt = 0; jt < 4; ++jt) {
#pragma unroll
      for (int r = 0; r < 4; ++r) {
        const float p = __expf((st[jt][nt][r] - mx) * 32.0f);
        sum += p;
        pb[jt][nt][r] = (_Float16)p;
      }
    }
    sum += __shfl_xor(sum, 16);
    sum += __shfl_xor(sum, 32);
    inv[nt] = 1.0f / sum;
  }

  // v^T A-frags: vA[kt][e] = v[kt*16 + g*4 + e][t]
  h16x4 vA[4];
#pragma unroll
  for (int kt = 0; kt < 4; ++kt)
#pragma unroll
    for (int e = 0; e < 4; ++e)
      vA[kt][e] = vsh[w][(kt * 16 + g * 4 + e) * RS + t];

  // out^T = v^T @ P^T; write per-frag into qsh (q reads are done), then
  // read back row-major and store coalesced.
#pragma unroll
  for (int it = 0; it < 4; ++it) {
    f32x4 ot = {0.f, 0.f, 0.f, 0.f};
#pragma unroll
    for (int kt = 0; kt < 4; ++kt)
      ot = __builtin_amdgcn_mfma_f32_16x16x16f16(vA[kt], pb[kt][it], ot, 0, 0, 0);
    h16x4 o;
#pragma unroll
    for (int r = 0; r < 4; ++r) o[r] = (_Float16)(ot[r] * inv[it]);
    *(h16x4*)&qsh[w][(it * 16 + t) * RS + g * 4] = o;
  }
  {
    const _Float16* orow = &qsh[w][lane * RS];
    h16x4 o0 = *(const h16x4*)(orow + 0);
    h16x4 o1 = *(const h16x4*)(orow + 4);
    h16x4 o2 = *(const h16x4*)(orow + 8);
    h16x4 o3 = *(const h16x4*)(orow + 12);
    h16x8 w0, w1;
#pragma unroll
    for (int e = 0; e < 4; ++e) {
      w0[e] = o0[e]; w0[4 + e] = o1[e];
      w1[e] = o2[e]; w1[4 + e] = o3[e];
    }
    *(h16x8*)(op + base + lane * 16) = w0;
    *(h16x8*)(op + base + lane * 16 + 8) = w1;
  }
}

extern "C" void kernel_launch(void* const* d_in, const int* in_sizes, int n_in,
                              void* d_out, int out_size, void* d_ws, size_t ws_size,
                              hipStream_t stream) {
  const float* query = (const float*)d_in[0];
  const float* key_  = (const float*)d_in[1];
  const float* value = (const float*)d_in[2];
  const float* Wq    = (const float*)d_in[3];
  const float* bq    = (const float*)d_in[4];
  const float* Wk    = (const float*)d_in[5];
  const float* bk    = (const float*)d_in[6];
  const float* Wv    = (const float*)d_in[7];
  const float* bv    = (const float*)d_in[8];
  const float* Wo    = (const float*)d_in[9];
  const float* bo    = (const float*)d_in[10];

  constexpr size_t MW = 1024 * 1024;
  constexpr size_t MA = (size_t)16384 * 1024;

  _Float16* Wf = (_Float16*)d_ws;  // 4*MW fp16 = 8 MB
  const size_t needA = (4 * MW + 6 * MA) * sizeof(_Float16);  // 200 MB

  if (ws_size >= needA) {
    _Float16* xf   = Wf + 4 * MW;  // converted q,k,v inputs: 96 MB
    _Float16* proj = xf + 3 * MA;  // projected q,k,v: 96 MB
    _Float16* ao   = xf;           // alias: inputs dead after QKV GEMM
    // one conversion kernel for weights + activations (contiguous dst)
    k_cvt_all<<<53248, 256, 0, stream>>>(Wq, Wk, Wv, Wo, query, key_, value, Wf);
    k_gemm_qkv_256<<<dim3(256, 3), 512, 0, stream>>>(xf, Wf, bq, bk, bv, proj);
    k_attn<<<4096, 256, 0, stream>>>(proj, proj + MA, proj + 2 * MA, ao);
    k_gemm_out_256<<<256, 512, 0, stream>>>(ao, Wf + 3 * MW, bo, (float*)d_out);
  } else {
    _Float16* proj = Wf + 4 * MW;
    _Float16* ao   = proj + 3 * MA;
    k_cvt_w<<<dim3(1024, 4), 256, 0, stream>>>(Wq, Wk, Wv, Wo, Wf);
    k_gemm_qkv_f32_legacy<<<dim3(1024, 3), 256, 0, stream>>>(query, key_, value, Wf,
                                                             bq, bk, bv, proj);
    k_attn<<<4096, 256, 0, stream>>>(proj, proj + MA, proj + 2 * MA, ao);
    k_gemm_out_256<<<256, 512, 0, stream>>>(ao, Wf + 3 * MW, bo, (float*)d_out);
  }
}